// Round 4
// baseline (250.715 us; speedup 1.0000x reference)
//
#include <hip/hip_runtime.h>
#include <math.h>

#define NV 5000   // nodes
#define BATCH 16
#define DD 12     // input feature dim
#define HH 64     // hidden dim
#define KK 30     // virtual nodes
#define NODES (BATCH * NV)

// ---------------- Kernel A: s[m] = adj[m,m] / deg[m] ----------------
__global__ __launch_bounds__(256) void s_kernel(const float* __restrict__ adj,
                                                const float* __restrict__ adjk1,
                                                float* __restrict__ s) {
    const int m = blockIdx.x;
    const float4* row = reinterpret_cast<const float4*>(adj + (size_t)m * NV);
    float acc = 0.f;
    for (int i = threadIdx.x; i < NV / 4; i += 256) {
        float4 v = row[i];
        acc += (v.x + v.y) + (v.z + v.w);
    }
    for (int off = 32; off > 0; off >>= 1) acc += __shfl_down(acc, off, 64);
    __shared__ float part[4];
    if ((threadIdx.x & 63) == 0) part[threadIdx.x >> 6] = acc;
    __syncthreads();
    if (threadIdx.x == 0) {
        float deg = (part[0] + part[1]) + (part[2] + part[3]);
        float cs = 0.f;
        #pragma unroll
        for (int k = 0; k < KK; ++k) cs += adjk1[(size_t)k * NV + m];
        deg += cs;
        s[m] = adj[(size_t)m * NV + m] / deg;
    }
}

// ---------------- activation: tanh(A) * sigmoid(C) ----------------
// Args are ~1e-3 (bounded by s ~ 4e-4, zero biases). Taylor polys are exact to
// fp32 rounding for |x|<=0.04 (rel err <= 2e-10). Cold exec-masked fallback to
// accurate routines for larger args. libm tanhf required in fallback: an
// expf-based tanh returns 0 for tiny args (round-0 failure).
__device__ __forceinline__ float act(float A, float C) {
    float a2 = A * A;
    float th = A * fmaf(a2, fmaf(a2, 0.13333334f, -0.33333334f), 1.0f);
    float c2 = C * C;
    float sg = fmaf(C, fmaf(c2, -0.020833334f, 0.25f), 0.5f);
    if (__builtin_expect(fabsf(A) > 0.04f, 0)) th = tanhf(A);
    if (__builtin_expect(fabsf(C) > 0.04f, 0)) sg = 1.0f / (1.0f + __expf(-C));
    return th * sg;
}

// ---------------- Kernel B: lane = node; weights via SMEM (s_load) ----------
// 64-thread blocks (1 wave, no barriers). Each lane owns one node and holds
// 128 fp32 accumulators (aa/cc) in VGPRs. Weight row W[k][0..63] is
// wave-uniform -> scalar s_load_dwordx16 on the SMEM pipe; inner FMAs are
// v_fmac_f32 v,s,v (independent -> dense issue). o between layers lives in a
// 16 KiB XOR-swizzled LDS tile: word addr = node*64 + (ch ^ (node&31)).
// All phases conflict-free:
//   epilogue write (ch static, lane varies): bank = ch ^ (lane&31) -> distinct
//   k-loop read   (k fixed, lane varies):    bank = k  ^ (lane&31) -> distinct
//   output read   (q fixed, lane = ch):      bank = lane ^ (q&31)  -> distinct
__global__ __launch_bounds__(64) void gcn_kernel(
    const float* __restrict__ x, const float* __restrict__ s,
    const float* __restrict__ W1, const float* __restrict__ b1,
    const float* __restrict__ W11, const float* __restrict__ b11,
    const float* __restrict__ W2, const float* __restrict__ b2,
    const float* __restrict__ W22, const float* __restrict__ b22,
    const float* __restrict__ W3, const float* __restrict__ b3,
    const float* __restrict__ W33, const float* __restrict__ b33,
    float* __restrict__ out) {
    __shared__ float ot[64 * HH];   // [node][ch ^ (node&31)] : 16 KiB

    const int lane = threadIdx.x;
    const int g = blockIdx.x * 64 + lane;      // flat node id (b*NV + m)
    const float sv = s[g % NV];
    const int swz = lane & 31;

    float aa[HH], cc[HH];

    // ---- Layer 1: D=12 -> H=64 ----
    float xr[DD];
    {
        const float4* xp = reinterpret_cast<const float4*>(x + (size_t)g * DD);
        float4 v0 = xp[0], v1 = xp[1], v2 = xp[2];
        xr[0] = v0.x; xr[1] = v0.y; xr[2] = v0.z;  xr[3] = v0.w;
        xr[4] = v1.x; xr[5] = v1.y; xr[6] = v1.z;  xr[7] = v1.w;
        xr[8] = v2.x; xr[9] = v2.y; xr[10] = v2.z; xr[11] = v2.w;
    }
    #pragma unroll
    for (int ch = 0; ch < HH; ++ch) { aa[ch] = 0.f; cc[ch] = 0.f; }
    #pragma unroll
    for (int k = 0; k < DD; ++k) {
        const float xv = xr[k];
        const float* __restrict__ wr  = W1  + k * HH;   // wave-uniform row
        #pragma unroll
        for (int ch = 0; ch < HH; ++ch) aa[ch] = fmaf(xv, wr[ch], aa[ch]);
        const float* __restrict__ wwr = W11 + k * HH;
        #pragma unroll
        for (int ch = 0; ch < HH; ++ch) cc[ch] = fmaf(xv, wwr[ch], cc[ch]);
    }
    #pragma unroll
    for (int ch = 0; ch < HH; ++ch)
        ot[lane * HH + (ch ^ swz)] =
            act(fmaf(sv, aa[ch], b1[ch]), fmaf(sv, cc[ch], b11[ch]));

    // ---- Layers 2 and 3: H=64 -> H=64 (gated) ----
    #define MLAYER(W_, WW_, b_, bb_, FINAL)                                    \
    {                                                                          \
        _Pragma("unroll")                                                      \
        for (int ch = 0; ch < HH; ++ch) { aa[ch] = 0.f; cc[ch] = 0.f; }        \
        float ov = ot[lane * HH + (0 ^ swz)];                                  \
        for (int k = 0; k < HH; ++k) {                                         \
            float ovn = ot[lane * HH + (((k + 1) & 63) ^ swz)];                \
            const float* __restrict__ wr  = W_  + k * HH;                      \
            _Pragma("unroll")                                                  \
            for (int ch = 0; ch < HH; ++ch) aa[ch] = fmaf(ov, wr[ch], aa[ch]); \
            const float* __restrict__ wwr = WW_ + k * HH;                      \
            _Pragma("unroll")                                                  \
            for (int ch = 0; ch < HH; ++ch) cc[ch] = fmaf(ov, wwr[ch], cc[ch]);\
            ov = ovn;                                                          \
        }                                                                      \
        _Pragma("unroll")                                                      \
        for (int ch = 0; ch < HH; ++ch)                                        \
            ot[lane * HH + (ch ^ swz)] =                                       \
                act(fmaf(sv, aa[ch], b_[ch]), fmaf(sv, cc[ch], bb_[ch]));      \
    }

    MLAYER(W2, W22, b2, b22, 0)
    MLAYER(W3, W33, b3, b33, 1)
    #undef MLAYER

    // ---- coalesced output: out[node q][ch = lane] ----
    const size_t ob = (size_t)blockIdx.x * (64 * HH);
    for (int q = 0; q < 64; ++q)
        out[ob + (size_t)q * HH + lane] = ot[q * HH + (lane ^ (q & 31))];
}

extern "C" void kernel_launch(void* const* d_in, const int* in_sizes, int n_in,
                              void* d_out, int out_size, void* d_ws, size_t ws_size,
                              hipStream_t stream) {
    const float* x     = (const float*)d_in[0];
    const float* adj   = (const float*)d_in[1];
    const float* adjk1 = (const float*)d_in[2];
    const float* W1  = (const float*)d_in[3];  const float* b1  = (const float*)d_in[4];
    const float* W11 = (const float*)d_in[5];  const float* b11 = (const float*)d_in[6];
    const float* W2  = (const float*)d_in[7];  const float* b2  = (const float*)d_in[8];
    const float* W22 = (const float*)d_in[9];  const float* b22 = (const float*)d_in[10];
    const float* W3  = (const float*)d_in[11]; const float* b3  = (const float*)d_in[12];
    const float* W33 = (const float*)d_in[13]; const float* b33 = (const float*)d_in[14];
    float* out = (float*)d_out;
    float* s = (float*)d_ws;  // 5000 floats scratch

    s_kernel<<<NV, 256, 0, stream>>>(adj, adjk1, s);
    gcn_kernel<<<NODES / 64, 64, 0, stream>>>(x, s, W1, b1, W11, b11,
                                              W2, b2, W22, b22, W3, b3, W33, b33, out);
}

// Round 6
// 126.303 us; speedup vs baseline: 1.9850x; 1.9850x over previous
//
#include <hip/hip_runtime.h>
#include <math.h>

#define NV 5000   // nodes
#define BATCH 16
#define DD 12     // input feature dim
#define HH 64     // hidden dim
#define KK 30     // virtual nodes
#define NODES (BATCH * NV)
#define CPW 16    // channels per wave (4 waves cover 64 channels)

// ---------------- Kernel A: s[m] = adj[m,m] / deg[m] ----------------
__global__ __launch_bounds__(256) void s_kernel(const float* __restrict__ adj,
                                                const float* __restrict__ adjk1,
                                                float* __restrict__ s) {
    const int m = blockIdx.x;
    const float4* row = reinterpret_cast<const float4*>(adj + (size_t)m * NV);
    float acc = 0.f;
    for (int i = threadIdx.x; i < NV / 4; i += 256) {
        float4 v = row[i];
        acc += (v.x + v.y) + (v.z + v.w);
    }
    for (int off = 32; off > 0; off >>= 1) acc += __shfl_down(acc, off, 64);
    __shared__ float part[4];
    if ((threadIdx.x & 63) == 0) part[threadIdx.x >> 6] = acc;
    __syncthreads();
    if (threadIdx.x == 0) {
        float deg = (part[0] + part[1]) + (part[2] + part[3]);
        float cs = 0.f;
        #pragma unroll
        for (int k = 0; k < KK; ++k) cs += adjk1[(size_t)k * NV + m];
        deg += cs;
        s[m] = adj[(size_t)m * NV + m] / deg;
    }
}

// ---------------- activation: tanh(A) * sigmoid(C) ----------------
// Args ~1e-3 (bounded by s ~ 4e-4). Taylor exact to fp32 rounding for
// |x|<=0.04; cold exec-masked fallback for larger args. libm tanhf required in
// fallback (expf-based tanh flushes tiny args to 0 -> the round-0 failure).
__device__ __forceinline__ float act(float A, float C) {
    float a2 = A * A;
    float th = A * fmaf(a2, fmaf(a2, 0.13333334f, -0.33333334f), 1.0f);
    float c2 = C * C;
    float sg = fmaf(C, fmaf(c2, -0.020833334f, 0.25f), 0.5f);
    if (__builtin_expect(fabsf(A) > 0.04f, 0)) th = tanhf(A);
    if (__builtin_expect(fabsf(C) > 0.04f, 0)) sg = 1.0f / (1.0f + __expf(-C));
    return th * sg;
}

// ---------------- Kernel B: lane=node, channel-split waves ----------------
// Block = 256 threads = 4 waves over the SAME 64 nodes; wave w owns output
// channels [16w, 16w+16). Weight rows are wave-uniform -> s_load into a small
// (32-SGPR) window per k-step, leaving SGPR headroom for scalar prefetch
// (round-4 used 128 SGPRs/k and serialized on K$ latency). o between layers
// lives in a 16 KiB XOR-swizzled LDS tile: word addr = node*64 + (ch^(node&31)).
//   write (ci static, lane varies): bank = (c0+ci)^(lane&31) -> distinct
//   read  (k fixed, lane varies):   bank = k^(lane&31)       -> distinct
//   epilogue (node uniform, lane=ch): bank = lane^(node&31)  -> distinct
__global__ __launch_bounds__(256) void gcn_kernel(
    const float* __restrict__ x, const float* __restrict__ s,
    const float* __restrict__ W1, const float* __restrict__ b1,
    const float* __restrict__ W11, const float* __restrict__ b11,
    const float* __restrict__ W2, const float* __restrict__ b2,
    const float* __restrict__ W22, const float* __restrict__ b22,
    const float* __restrict__ W3, const float* __restrict__ b3,
    const float* __restrict__ W33, const float* __restrict__ b33,
    float* __restrict__ out) {
    __shared__ float ot[64 * HH];   // 16 KiB

    const int tid = threadIdx.x;
    const int lane = tid & 63;
    const int c0 = __builtin_amdgcn_readfirstlane((tid >> 6) * CPW);
    const int g = blockIdx.x * 64 + lane;      // flat node id (b*NV + m)
    const float sv = s[g % NV];
    const int swz = lane & 31;

    float aa[CPW], cc[CPW];

    // ---- Layer 1: D=12 -> H=64 (this wave's 16 channels) ----
    float xr[DD];
    {
        const float4* xp = reinterpret_cast<const float4*>(x + (size_t)g * DD);
        float4 v0 = xp[0], v1 = xp[1], v2 = xp[2];
        xr[0] = v0.x; xr[1] = v0.y; xr[2] = v0.z;  xr[3] = v0.w;
        xr[4] = v1.x; xr[5] = v1.y; xr[6] = v1.z;  xr[7] = v1.w;
        xr[8] = v2.x; xr[9] = v2.y; xr[10] = v2.z; xr[11] = v2.w;
    }
    #pragma unroll
    for (int ci = 0; ci < CPW; ++ci) { aa[ci] = 0.f; cc[ci] = 0.f; }
    #pragma unroll
    for (int k = 0; k < DD; ++k) {
        const float xv = xr[k];
        const float* __restrict__ wr  = W1  + k * HH + c0;  // wave-uniform
        const float* __restrict__ wwr = W11 + k * HH + c0;
        #pragma unroll
        for (int ci = 0; ci < CPW; ++ci) {
            aa[ci] = fmaf(xv, wr[ci],  aa[ci]);
            cc[ci] = fmaf(xv, wwr[ci], cc[ci]);
        }
    }
    #pragma unroll
    for (int ci = 0; ci < CPW; ++ci)
        ot[lane * HH + ((c0 + ci) ^ swz)] =
            act(fmaf(sv, aa[ci], b1[c0 + ci]), fmaf(sv, cc[ci], b11[c0 + ci]));
    __syncthreads();

    // ---- Layers 2 and 3: H=64 -> H=64 (gated) ----
    #define MLAYER(W_, WW_, b_, bb_)                                           \
    {                                                                          \
        _Pragma("unroll")                                                      \
        for (int ci = 0; ci < CPW; ++ci) { aa[ci] = 0.f; cc[ci] = 0.f; }       \
        _Pragma("unroll 4")                                                    \
        for (int k = 0; k < HH; ++k) {                                         \
            const float ov = ot[lane * HH + (k ^ swz)];                        \
            const float* __restrict__ wr  = W_  + k * HH + c0;                 \
            const float* __restrict__ wwr = WW_ + k * HH + c0;                 \
            _Pragma("unroll")                                                  \
            for (int ci = 0; ci < CPW; ++ci) {                                 \
                aa[ci] = fmaf(ov, wr[ci],  aa[ci]);                            \
                cc[ci] = fmaf(ov, wwr[ci], cc[ci]);                            \
            }                                                                  \
        }                                                                      \
        __syncthreads();                                                       \
        _Pragma("unroll")                                                      \
        for (int ci = 0; ci < CPW; ++ci)                                       \
            ot[lane * HH + ((c0 + ci) ^ swz)] =                                \
                act(fmaf(sv, aa[ci], b_[c0 + ci]),                             \
                    fmaf(sv, cc[ci], bb_[c0 + ci]));                           \
        __syncthreads();                                                       \
    }

    MLAYER(W2, W22, b2, b22)
    MLAYER(W3, W33, b3, b33)
    #undef MLAYER

    // ---- coalesced output via LDS transpose ----
    // Block owns 64 nodes x 64 ch = 4096 outputs = 16 iters x 256 threads.
    // (Round-5 bug: used r*1024+tid -> wrote 4x out of bounds.)
    const size_t ob = (size_t)blockIdx.x * (64 * HH);
    #pragma unroll
    for (int r = 0; r < 16; ++r) {
        const int flat = r * 256 + tid;      // [0, 4096)
        const int node = flat >> 6;          // wave-uniform (r*4 + wid)
        const int ch = flat & 63;            // = lane
        out[ob + flat] = ot[node * HH + (ch ^ (node & 31))];
    }
}

extern "C" void kernel_launch(void* const* d_in, const int* in_sizes, int n_in,
                              void* d_out, int out_size, void* d_ws, size_t ws_size,
                              hipStream_t stream) {
    const float* x     = (const float*)d_in[0];
    const float* adj   = (const float*)d_in[1];
    const float* adjk1 = (const float*)d_in[2];
    const float* W1  = (const float*)d_in[3];  const float* b1  = (const float*)d_in[4];
    const float* W11 = (const float*)d_in[5];  const float* b11 = (const float*)d_in[6];
    const float* W2  = (const float*)d_in[7];  const float* b2  = (const float*)d_in[8];
    const float* W22 = (const float*)d_in[9];  const float* b22 = (const float*)d_in[10];
    const float* W3  = (const float*)d_in[11]; const float* b3  = (const float*)d_in[12];
    const float* W33 = (const float*)d_in[13]; const float* b33 = (const float*)d_in[14];
    float* out = (float*)d_out;
    float* s = (float*)d_ws;  // 5000 floats scratch

    s_kernel<<<NV, 256, 0, stream>>>(adj, adjk1, s);
    gcn_kernel<<<NODES / 64, 256, 0, stream>>>(x, s, W1, b1, W11, b11,
                                               W2, b2, W22, b22, W3, b3, W33, b33, out);
}

// Round 7
// 120.204 us; speedup vs baseline: 2.0857x; 1.0507x over previous
//
#include <hip/hip_runtime.h>
#include <math.h>

#define NV 5000   // nodes
#define BATCH 16
#define DD 12     // input feature dim
#define HH 64     // hidden dim
#define KK 30     // virtual nodes
#define NODES (BATCH * NV)
#define CPW 16    // channels per wave (4 waves cover 64 channels)

// ---------------- Kernel A: s[m] = adj[m,m] / deg[m] ----------------
__global__ __launch_bounds__(256) void s_kernel(const float* __restrict__ adj,
                                                const float* __restrict__ adjk1,
                                                float* __restrict__ s) {
    const int m = blockIdx.x;
    const float4* row = reinterpret_cast<const float4*>(adj + (size_t)m * NV);
    float acc = 0.f;
    for (int i = threadIdx.x; i < NV / 4; i += 256) {
        float4 v = row[i];
        acc += (v.x + v.y) + (v.z + v.w);
    }
    for (int off = 32; off > 0; off >>= 1) acc += __shfl_down(acc, off, 64);
    __shared__ float part[4];
    if ((threadIdx.x & 63) == 0) part[threadIdx.x >> 6] = acc;
    __syncthreads();
    if (threadIdx.x == 0) {
        float deg = (part[0] + part[1]) + (part[2] + part[3]);
        float cs = 0.f;
        #pragma unroll
        for (int k = 0; k < KK; ++k) cs += adjk1[(size_t)k * NV + m];
        deg += cs;
        s[m] = adj[(size_t)m * NV + m] / deg;
    }
}

// ---------------- activation: tanh(A) * sigmoid(C) ----------------
// Args ~1e-3 (bounded by s ~ 4e-4). Taylor exact to fp32 rounding for
// |x|<=0.04; cold exec-masked fallback for larger args. libm tanhf required in
// fallback (expf-based tanh flushes tiny args to 0 -> the round-0 failure).
__device__ __forceinline__ float act(float A, float C) {
    float a2 = A * A;
    float th = A * fmaf(a2, fmaf(a2, 0.13333334f, -0.33333334f), 1.0f);
    float c2 = C * C;
    float sg = fmaf(C, fmaf(c2, -0.020833334f, 0.25f), 0.5f);
    if (__builtin_expect(fabsf(A) > 0.04f, 0)) th = tanhf(A);
    if (__builtin_expect(fabsf(C) > 0.04f, 0)) sg = 1.0f / (1.0f + __expf(-C));
    return th * sg;
}

// ---------------- Kernel B: lane=node, channel-split waves ----------------
// Block = 256 threads = 4 waves over the SAME 64 nodes; wave w owns output
// channels [16w, 16w+16). Weight rows are wave-uniform -> s_load into a
// 32-SGPR window. CRITICAL (round-6 lesson): keep the live weight window at
// ONE k-step. unroll>1 (or unhindered full-unroll scheduling) demands
// 128-384 weight SGPRs -> allocator spills SGPRs via v_writelane/v_readlane
// (VALU!) -> 4.3x VALU bloat (round 6: 116us, VALUBusy 68% vs 18us FMA floor).
//   MLAYER: #pragma unroll 1  -> 32 live weight SGPRs.
//   Layer1: full unroll needed (xr static), but sched_barrier(0) between
//           k-steps stops cross-k s_load hoisting.
// o between layers in a 16 KiB XOR-swizzled LDS tile:
//   word addr = node*64 + (ch ^ (node&31)); all phases conflict-free.
__global__ __launch_bounds__(256) void gcn_kernel(
    const float* __restrict__ x, const float* __restrict__ s,
    const float* __restrict__ W1, const float* __restrict__ b1,
    const float* __restrict__ W11, const float* __restrict__ b11,
    const float* __restrict__ W2, const float* __restrict__ b2,
    const float* __restrict__ W22, const float* __restrict__ b22,
    const float* __restrict__ W3, const float* __restrict__ b3,
    const float* __restrict__ W33, const float* __restrict__ b33,
    float* __restrict__ out) {
    __shared__ float ot[64 * HH];   // 16 KiB

    const int tid = threadIdx.x;
    const int lane = tid & 63;
    const int c0 = __builtin_amdgcn_readfirstlane((tid >> 6) * CPW);
    const int g = blockIdx.x * 64 + lane;      // flat node id (b*NV + m)
    const float sv = s[g % NV];
    const int swz = lane & 31;

    float aa[CPW], cc[CPW];

    // ---- Layer 1: D=12 -> H=64 (this wave's 16 channels) ----
    float xr[DD];
    {
        const float4* xp = reinterpret_cast<const float4*>(x + (size_t)g * DD);
        float4 v0 = xp[0], v1 = xp[1], v2 = xp[2];
        xr[0] = v0.x; xr[1] = v0.y; xr[2] = v0.z;  xr[3] = v0.w;
        xr[4] = v1.x; xr[5] = v1.y; xr[6] = v1.z;  xr[7] = v1.w;
        xr[8] = v2.x; xr[9] = v2.y; xr[10] = v2.z; xr[11] = v2.w;
    }
    #pragma unroll
    for (int ci = 0; ci < CPW; ++ci) { aa[ci] = 0.f; cc[ci] = 0.f; }
    #pragma unroll
    for (int k = 0; k < DD; ++k) {
        const float xv = xr[k];
        const float* __restrict__ wr  = W1  + k * HH + c0;  // wave-uniform
        const float* __restrict__ wwr = W11 + k * HH + c0;
        #pragma unroll
        for (int ci = 0; ci < CPW; ++ci) {
            aa[ci] = fmaf(xv, wr[ci],  aa[ci]);
            cc[ci] = fmaf(xv, wwr[ci], cc[ci]);
        }
        __builtin_amdgcn_sched_barrier(0);   // cap live s_load window at 1 k-step
    }
    #pragma unroll
    for (int ci = 0; ci < CPW; ++ci)
        ot[lane * HH + ((c0 + ci) ^ swz)] =
            act(fmaf(sv, aa[ci], b1[c0 + ci]), fmaf(sv, cc[ci], b11[c0 + ci]));
    __syncthreads();

    // ---- Layers 2 and 3: H=64 -> H=64 (gated) ----
    #define MLAYER(W_, WW_, b_, bb_)                                           \
    {                                                                          \
        _Pragma("unroll")                                                      \
        for (int ci = 0; ci < CPW; ++ci) { aa[ci] = 0.f; cc[ci] = 0.f; }       \
        _Pragma("unroll 1")                                                    \
        for (int k = 0; k < HH; ++k) {                                         \
            const float ov = ot[lane * HH + (k ^ swz)];                        \
            const float* __restrict__ wr  = W_  + k * HH + c0;                 \
            const float* __restrict__ wwr = WW_ + k * HH + c0;                 \
            _Pragma("unroll")                                                  \
            for (int ci = 0; ci < CPW; ++ci) {                                 \
                aa[ci] = fmaf(ov, wr[ci],  aa[ci]);                            \
                cc[ci] = fmaf(ov, wwr[ci], cc[ci]);                            \
            }                                                                  \
        }                                                                      \
        __syncthreads();                                                       \
        _Pragma("unroll")                                                      \
        for (int ci = 0; ci < CPW; ++ci)                                       \
            ot[lane * HH + ((c0 + ci) ^ swz)] =                                \
                act(fmaf(sv, aa[ci], b_[c0 + ci]),                             \
                    fmaf(sv, cc[ci], bb_[c0 + ci]));                           \
        __syncthreads();                                                       \
    }

    MLAYER(W2, W22, b2, b22)
    MLAYER(W3, W33, b3, b33)
    #undef MLAYER

    // ---- coalesced output via LDS transpose ----
    // Block owns 64 nodes x 64 ch = 4096 outputs = 16 iters x 256 threads.
    const size_t ob = (size_t)blockIdx.x * (64 * HH);
    #pragma unroll
    for (int r = 0; r < 16; ++r) {
        const int flat = r * 256 + tid;      // [0, 4096)
        const int node = flat >> 6;          // wave-uniform (r*4 + wid)
        const int ch = flat & 63;            // = lane
        out[ob + flat] = ot[node * HH + (ch ^ (node & 31))];
    }
}

extern "C" void kernel_launch(void* const* d_in, const int* in_sizes, int n_in,
                              void* d_out, int out_size, void* d_ws, size_t ws_size,
                              hipStream_t stream) {
    const float* x     = (const float*)d_in[0];
    const float* adj   = (const float*)d_in[1];
    const float* adjk1 = (const float*)d_in[2];
    const float* W1  = (const float*)d_in[3];  const float* b1  = (const float*)d_in[4];
    const float* W11 = (const float*)d_in[5];  const float* b11 = (const float*)d_in[6];
    const float* W2  = (const float*)d_in[7];  const float* b2  = (const float*)d_in[8];
    const float* W22 = (const float*)d_in[9];  const float* b22 = (const float*)d_in[10];
    const float* W3  = (const float*)d_in[11]; const float* b3  = (const float*)d_in[12];
    const float* W33 = (const float*)d_in[13]; const float* b33 = (const float*)d_in[14];
    float* out = (float*)d_out;
    float* s = (float*)d_ws;  // 5000 floats scratch

    s_kernel<<<NV, 256, 0, stream>>>(adj, adjk1, s);
    gcn_kernel<<<NODES / 64, 256, 0, stream>>>(x, s, W1, b1, W11, b11,
                                               W2, b2, W22, b22, W3, b3, W33, b33, out);
}

// Round 8
// 100.099 us; speedup vs baseline: 2.5047x; 1.2009x over previous
//
#include <hip/hip_runtime.h>
#include <math.h>

#define NV 5000   // nodes
#define BATCH 16
#define DD 12     // input feature dim
#define HH 64     // hidden dim
#define KK 30     // virtual nodes
#define NODES (BATCH * NV)
#define NPW 8               // nodes per wave-group
#define NGROUPS (NODES / NPW)   // 10000
#define GRID 1024           // 2 blocks/CU x 256 CU (512-thread blocks)
#define WSTRIDE (GRID * 8)  // total waves = 8192

// ---------------- Kernel A: s[m] = adj[m,m] / deg[m] ----------------
__global__ __launch_bounds__(256) void s_kernel(const float* __restrict__ adj,
                                                const float* __restrict__ adjk1,
                                                float* __restrict__ s) {
    const int m = blockIdx.x;
    const float4* row = reinterpret_cast<const float4*>(adj + (size_t)m * NV);
    float acc = 0.f;
    for (int i = threadIdx.x; i < NV / 4; i += 256) {
        float4 v = row[i];
        acc += (v.x + v.y) + (v.z + v.w);
    }
    for (int off = 32; off > 0; off >>= 1) acc += __shfl_down(acc, off, 64);
    __shared__ float part[4];
    if ((threadIdx.x & 63) == 0) part[threadIdx.x >> 6] = acc;
    __syncthreads();
    if (threadIdx.x == 0) {
        float deg = (part[0] + part[1]) + (part[2] + part[3]);
        float cs = 0.f;
        #pragma unroll
        for (int k = 0; k < KK; ++k) cs += adjk1[(size_t)k * NV + m];
        deg += cs;
        s[m] = adj[(size_t)m * NV + m] / deg;
    }
}

// ---------------- activation: tanh(A) * sigmoid(C) ----------------
// Args ~1e-3 (bounded by s ~ 4e-4). Taylor exact to fp32 rounding for
// |x|<=0.04; cold exec-masked fallback for larger args. libm tanhf required in
// fallback (expf-based tanh flushes tiny args to 0 -> the round-0 failure).
__device__ __forceinline__ float act(float A, float C) {
    float a2 = A * A;
    float th = A * fmaf(a2, fmaf(a2, 0.13333334f, -0.33333334f), 1.0f);
    float c2 = C * C;
    float sg = fmaf(C, fmaf(c2, -0.020833334f, 0.25f), 0.5f);
    if (__builtin_expect(fabsf(A) > 0.04f, 0)) th = tanhf(A);
    if (__builtin_expect(fabsf(C) > 0.04f, 0)) sg = 1.0f / (1.0f + __expf(-C));
    return th * sg;
}

// explicit lane-extract: value of v in lane l, materialized in an SGPR
__device__ __forceinline__ float rdl(float v, int l) {
    return __int_as_float(__builtin_amdgcn_readlane(__float_as_int(v), l));
}

// ---------------- Kernel B: lane = channel, o stays in registers ----------
// Round-7 lesson: the compiler does NOT scalarize "uniform" global weight
// loads -> per-lane VMEM storm (3.5x VALU bloat). So: make every residence
// explicit. lane c holds channel c of all NPW nodes; layer output buf[n] is
// produced in exactly the residence the next layer consumes (lane k = channel
// k) -> k-operand extracted with ONE v_readlane (explicit builtin, SGPR
// result), weights per-lane from LDS as ds_read_b128 of 4 k-steps
// (transposed-interleaved WT[kb][c][j] = W[4kb+j][c], conflict-free).
// Per kb: 2 ds_read_b128 (24 LDS-cyc) vs 96 VALU (192 cyc) -> LDS pipe 50%.
// No LDS for activations, no barriers after staging, coalesced stores.
__global__ __launch_bounds__(512, 4) void gcn_kernel(
    const float* __restrict__ x, const float* __restrict__ s,
    const float* __restrict__ W1, const float* __restrict__ b1,
    const float* __restrict__ W11, const float* __restrict__ b11,
    const float* __restrict__ W2, const float* __restrict__ b2,
    const float* __restrict__ W22, const float* __restrict__ b22,
    const float* __restrict__ W3, const float* __restrict__ b3,
    const float* __restrict__ W33, const float* __restrict__ b33,
    float* __restrict__ out) {
    __shared__ float WT1[3 * 64 * 4], WT11[3 * 64 * 4];        // 3 KiB each
    __shared__ float WT2[16 * 64 * 4], WT22[16 * 64 * 4];      // 16 KiB each
    __shared__ float WT3[16 * 64 * 4], WT33[16 * 64 * 4];      // total 70 KiB

    const int tid = threadIdx.x;
    const int lane = tid & 63;
    const int wid = tid >> 6;

    // ---- stage all weights, transposed-interleaved ----
    #pragma unroll
    for (int p = 0; p < 2; ++p) {
        const int t = tid + p * 512;          // 1024 (kb,c) pairs per matrix
        const int r0 = (t >> 6) * 4, c = t & 63;
        *(float4*)&WT2[t * 4] = make_float4(W2[(r0 + 0) * 64 + c], W2[(r0 + 1) * 64 + c],
                                            W2[(r0 + 2) * 64 + c], W2[(r0 + 3) * 64 + c]);
        *(float4*)&WT22[t * 4] = make_float4(W22[(r0 + 0) * 64 + c], W22[(r0 + 1) * 64 + c],
                                             W22[(r0 + 2) * 64 + c], W22[(r0 + 3) * 64 + c]);
        *(float4*)&WT3[t * 4] = make_float4(W3[(r0 + 0) * 64 + c], W3[(r0 + 1) * 64 + c],
                                            W3[(r0 + 2) * 64 + c], W3[(r0 + 3) * 64 + c]);
        *(float4*)&WT33[t * 4] = make_float4(W33[(r0 + 0) * 64 + c], W33[(r0 + 1) * 64 + c],
                                             W33[(r0 + 2) * 64 + c], W33[(r0 + 3) * 64 + c]);
    }
    if (tid < 192) {                          // 192 (kb,c) pairs (k = 0..11)
        const int r0 = (tid >> 6) * 4, c = tid & 63;
        *(float4*)&WT1[tid * 4] = make_float4(W1[(r0 + 0) * 64 + c], W1[(r0 + 1) * 64 + c],
                                              W1[(r0 + 2) * 64 + c], W1[(r0 + 3) * 64 + c]);
        *(float4*)&WT11[tid * 4] = make_float4(W11[(r0 + 0) * 64 + c], W11[(r0 + 1) * 64 + c],
                                               W11[(r0 + 2) * 64 + c], W11[(r0 + 3) * 64 + c]);
    }
    __syncthreads();

    const float bva1 = b1[lane], bvb1 = b11[lane];
    const float bva2 = b2[lane], bvb2 = b22[lane];
    const float bva3 = b3[lane], bvb3 = b33[lane];

    float buf[NPW], aa[NPW], cc[NPW];

    #define LAYER(WTa, WTb, NKB, bva, bvb)                                     \
    {                                                                          \
        _Pragma("unroll")                                                      \
        for (int n = 0; n < NPW; ++n) { aa[n] = 0.f; cc[n] = 0.f; }            \
        float4 wq = *(const float4*)&WTa[lane * 4];                            \
        float4 wwq = *(const float4*)&WTb[lane * 4];                           \
        _Pragma("unroll 1")                                                    \
        for (int kb = 0; kb < NKB; ++kb) {                                     \
            const int kbn = (kb + 1 < NKB) ? kb + 1 : kb;                      \
            float4 wqn = *(const float4*)&WTa[(kbn * 64 + lane) * 4];          \
            float4 wwqn = *(const float4*)&WTb[(kbn * 64 + lane) * 4];         \
            const float wa[4] = {wq.x, wq.y, wq.z, wq.w};                      \
            const float wb[4] = {wwq.x, wwq.y, wwq.z, wwq.w};                  \
            _Pragma("unroll")                                                  \
            for (int j = 0; j < 4; ++j) {                                      \
                const int kk = 4 * kb + j;                                     \
                _Pragma("unroll")                                              \
                for (int n = 0; n < NPW; ++n) {                                \
                    const float ov = rdl(buf[n], kk);                          \
                    aa[n] = fmaf(ov, wa[j], aa[n]);                            \
                    cc[n] = fmaf(ov, wb[j], cc[n]);                            \
                }                                                              \
            }                                                                  \
            wq = wqn; wwq = wwqn;                                              \
        }                                                                      \
        _Pragma("unroll")                                                      \
        for (int n = 0; n < NPW; ++n) {                                        \
            const float svn = rdl(svl, n);                                     \
            buf[n] = act(fmaf(svn, aa[n], bva), fmaf(svn, cc[n], bvb));        \
        }                                                                      \
    }

    // wave-level grid-stride over 8-node groups (amortizes staging, no tail)
    for (int grp = blockIdx.x * 8 + wid; grp < NGROUPS; grp += WSTRIDE) {
        const int g0 = grp * NPW;
        // lane n<8 holds s for node g0+n (replicated mod 8); rdl(svl,n) extracts
        const float svl = s[(g0 + (lane & 7)) % NV];
        // lane d<12 holds x[node n][d] in buf[n]
        #pragma unroll
        for (int n = 0; n < NPW; ++n)
            buf[n] = (lane < DD) ? x[(size_t)(g0 + n) * DD + lane] : 0.f;

        LAYER(WT1, WT11, 3, bva1, bvb1)
        LAYER(WT2, WT22, 16, bva2, bvb2)
        LAYER(WT3, WT33, 16, bva3, bvb3)

        #pragma unroll
        for (int n = 0; n < NPW; ++n)
            out[(size_t)(g0 + n) * HH + lane] = buf[n];   // coalesced 256B
    }
    #undef LAYER
}

extern "C" void kernel_launch(void* const* d_in, const int* in_sizes, int n_in,
                              void* d_out, int out_size, void* d_ws, size_t ws_size,
                              hipStream_t stream) {
    const float* x     = (const float*)d_in[0];
    const float* adj   = (const float*)d_in[1];
    const float* adjk1 = (const float*)d_in[2];
    const float* W1  = (const float*)d_in[3];  const float* b1  = (const float*)d_in[4];
    const float* W11 = (const float*)d_in[5];  const float* b11 = (const float*)d_in[6];
    const float* W2  = (const float*)d_in[7];  const float* b2  = (const float*)d_in[8];
    const float* W22 = (const float*)d_in[9];  const float* b22 = (const float*)d_in[10];
    const float* W3  = (const float*)d_in[11]; const float* b3  = (const float*)d_in[12];
    const float* W33 = (const float*)d_in[13]; const float* b33 = (const float*)d_in[14];
    float* out = (float*)d_out;
    float* s = (float*)d_ws;  // 5000 floats scratch

    s_kernel<<<NV, 256, 0, stream>>>(adj, adjk1, s);
    gcn_kernel<<<GRID, 512, 0, stream>>>(x, s, W1, b1, W11, b11,
                                         W2, b2, W22, b22, W3, b3, W33, b33, out);
}

// Round 9
// 45.774 us; speedup vs baseline: 5.4773x; 2.1868x over previous
//
#include <hip/hip_runtime.h>
#include <math.h>

#define NV 5000   // nodes
#define BATCH 16
#define DD 12     // input feature dim
#define HH 64     // hidden dim
#define KK 30     // virtual nodes
#define NODES (BATCH * NV)   // 80000
#define NGRP (NODES / 16)    // 5000 wave-groups (16 nodes each)
#define BLOCKS (NGRP / 8)    // 625 blocks x 8 waves

typedef __attribute__((ext_vector_type(8))) short short8v;  // 8 bf16 (4 VGPR)
typedef __attribute__((ext_vector_type(4))) float f32x4;
typedef __attribute__((ext_vector_type(4))) int int4v;
union I4S8 { int4v i; short8v s; };

// ---------------- Kernel A: s[m] = adj[m,m] / deg[m] ----------------
__global__ __launch_bounds__(256) void s_kernel(const float* __restrict__ adj,
                                                const float* __restrict__ adjk1,
                                                float* __restrict__ s) {
    const int m = blockIdx.x;
    const float4* row = reinterpret_cast<const float4*>(adj + (size_t)m * NV);
    float acc = 0.f;
    for (int i = threadIdx.x; i < NV / 4; i += 256) {
        float4 v = row[i];
        acc += (v.x + v.y) + (v.z + v.w);
    }
    for (int off = 32; off > 0; off >>= 1) acc += __shfl_down(acc, off, 64);
    __shared__ float part[4];
    if ((threadIdx.x & 63) == 0) part[threadIdx.x >> 6] = acc;
    __syncthreads();
    if (threadIdx.x == 0) {
        float deg = (part[0] + part[1]) + (part[2] + part[3]);
        float cs = 0.f;
        #pragma unroll
        for (int k = 0; k < KK; ++k) cs += adjk1[(size_t)k * NV + m];
        deg += cs;
        s[m] = adj[(size_t)m * NV + m] / deg;
    }
}

// ---------------- helpers ----------------
__device__ __forceinline__ unsigned short bf16rne(float f) {
    unsigned u = __float_as_uint(f);
    u += 0x7FFFu + ((u >> 16) & 1u);          // round-to-nearest-even
    return (unsigned short)(u >> 16);
}
__device__ __forceinline__ int packbf(float lo, float hi) {
    return (int)((unsigned)bf16rne(lo) | ((unsigned)bf16rne(hi) << 16));
}
__device__ __forceinline__ float bperm(int addr, float v) {
    return __int_as_float(__builtin_amdgcn_ds_bpermute(addr, __float_as_int(v)));
}
// tanh(A)*sigmoid(C); args ~1e-3. Taylor exact to fp32 rounding for |x|<=0.04;
// cold fallback uses libm tanhf (expf-tanh flushes tiny args -> round-0 bug).
__device__ __forceinline__ float act(float A, float C) {
    float a2 = A * A;
    float th = A * fmaf(a2, fmaf(a2, 0.13333334f, -0.33333334f), 1.0f);
    float c2 = C * C;
    float sg = fmaf(C, fmaf(c2, -0.020833334f, 0.25f), 0.5f);
    if (__builtin_expect(fabsf(A) > 0.04f, 0)) th = tanhf(A);
    if (__builtin_expect(fabsf(C) > 0.04f, 0)) sg = 1.0f / (1.0f + __expf(-C));
    return th * sg;
}

// ---------------- Kernel B: MFMA, swapped orientation ----------------
// Per wave: 16 nodes (node = lane&15), all 64 out-chs. D[ch][node] = W^T o:
//  A-frag(mat,t,ks): lane supplies W[k][16t+(lane&15)], k=32ks+(lane>>4)*8+j
//  B-frag(ks):       lane supplies o[k][node], k as above, node=lane&15
//  D: ch = 16t + 4q + r (q=lane>>4, reg r), node = lane&15   [m89-verified]
// Inter-layer: o lives in D-layout regs ov[t][r]; B rebuilt with ds_bpermute
// (src lane = 16*(2(q&1)+(j>>2)) + col, tile = 2ks+(q>>1) via cndmask).
// Weights staged once/block into LDS in frag order (bf16). Biases in LDS.
__global__ __launch_bounds__(512, 4) void gcn_kernel(
    const float* __restrict__ x, const float* __restrict__ s,
    const float* __restrict__ W1, const float* __restrict__ b1,
    const float* __restrict__ W11, const float* __restrict__ b11,
    const float* __restrict__ W2, const float* __restrict__ b2,
    const float* __restrict__ W22, const float* __restrict__ b22,
    const float* __restrict__ W3, const float* __restrict__ b3,
    const float* __restrict__ W33, const float* __restrict__ b33,
    float* __restrict__ out) {
    __shared__ unsigned short WH[4 * 8 * 64 * 8];   // W2,W22,W3,W33 frags: 32 KiB
    __shared__ unsigned short WL[2 * 4 * 64 * 8];   // W1,W11 frags (K-padded): 8 KiB
    __shared__ float BIAS[6 * 64];                  // b1,b11,b2,b22,b3,b33: 1.5 KiB

    const int tid = threadIdx.x;

    // ---- stage H-layer weights into frag order (coalesced reads) ----
    {
        const float* HM[4] = {W2, W22, W3, W33};
        #pragma unroll
        for (int m = 0; m < 4; ++m) {
            const float* Wp = HM[m];
            for (int e = tid; e < 4096; e += 512) {
                const int k = e >> 6, c = e & 63;
                const int dst = ((m * 8 + (c >> 4) * 2 + (k >> 5)) * 64 +
                                 ((k >> 3) & 3) * 16 + (c & 15)) * 8 + (k & 7);
                WH[dst] = bf16rne(Wp[e]);
            }
        }
    }
    for (int e = tid; e < 2048; e += 512) *(unsigned*)&WL[e * 2] = 0u;  // zero-pad K
    if (tid < 64) BIAS[tid] = b1[tid];
    else if (tid < 128) BIAS[tid] = b11[tid & 63];
    else if (tid < 192) BIAS[tid] = b2[tid & 63];
    else if (tid < 256) BIAS[tid] = b22[tid & 63];
    else if (tid < 320) BIAS[tid] = b3[tid & 63];
    else if (tid < 384) BIAS[tid] = b33[tid & 63];
    __syncthreads();
    #pragma unroll
    for (int m = 0; m < 2; ++m) {
        const float* Wp = (m == 0) ? W1 : W11;
        for (int e = tid; e < 768; e += 512) {
            const int k = e >> 6, c = e & 63;
            const int dst = ((m * 4 + (c >> 4)) * 64 +
                             ((k >> 3) & 3) * 16 + (c & 15)) * 8 + (k & 7);
            WL[dst] = bf16rne(Wp[e]);
        }
    }
    __syncthreads();

    const int lane = tid & 63, wid = tid >> 6;
    const int q = lane >> 4, col = lane & 15;
    const int G = blockIdx.x * 8 + wid;        // group id [0,5000)
    const int node = G * 16 + col;             // flat node (b*NV+m)
    const float sv = s[node % NV];
    const int A0 = (32 * (q & 1) + col) * 4;   // bperm addr, j<4
    const int A1 = A0 + 64;                    //              j>=4
    const f32x4 zf = {0.f, 0.f, 0.f, 0.f};

    // ---- Layer 1: B = x (fp32 -> bf16), K padded 12->32 ----
    f32x4 xa = zf, xb = zf;
    {
        const float* xp = x + (size_t)node * DD;
        if (q == 0) { xa = *(const f32x4*)(xp); xb = *(const f32x4*)(xp + 4); }
        else if (q == 1) { xa = *(const f32x4*)(xp + 8); }
    }
    I4S8 bx;
    bx.i = (int4v){packbf(xa[0], xa[1]), packbf(xa[2], xa[3]),
                   packbf(xb[0], xb[1]), packbf(xb[2], xb[3])};

    f32x4 accA[4], accC[4];
    float ov[4][4];
    #pragma unroll
    for (int t = 0; t < 4; ++t) {
        short8v a0 = *(short8v*)&WL[((0 * 4 + t) * 64 + lane) * 8];
        short8v a1 = *(short8v*)&WL[((1 * 4 + t) * 64 + lane) * 8];
        accA[t] = __builtin_amdgcn_mfma_f32_16x16x32_bf16(a0, bx.s, zf, 0, 0, 0);
        accC[t] = __builtin_amdgcn_mfma_f32_16x16x32_bf16(a1, bx.s, zf, 0, 0, 0);
    }
    #pragma unroll
    for (int t = 0; t < 4; ++t) {
        f32x4 ba = *(f32x4*)&BIAS[0 * 64 + 16 * t + 4 * q];
        f32x4 bc = *(f32x4*)&BIAS[1 * 64 + 16 * t + 4 * q];
        #pragma unroll
        for (int r = 0; r < 4; ++r)
            ov[t][r] = act(fmaf(sv, accA[t][r], ba[r]), fmaf(sv, accC[t][r], bc[r]));
    }

    I4S8 B0, B1;
    #define BBUILD()                                                           \
    {                                                                          \
        _Pragma("unroll")                                                      \
        for (int ks = 0; ks < 2; ++ks) {                                       \
            int dw[4];                                                         \
            _Pragma("unroll")                                                  \
            for (int jp = 0; jp < 4; ++jp) {                                   \
                const int addr = (jp < 2) ? A0 : A1;                           \
                const int r0 = (2 * jp) & 3, r1 = (2 * jp + 1) & 3;            \
                float p0 = bperm(addr, ov[2 * ks][r0]);                        \
                float p1 = bperm(addr, ov[2 * ks + 1][r0]);                    \
                float v0 = (lane & 32) ? p1 : p0;                              \
                float p2 = bperm(addr, ov[2 * ks][r1]);                        \
                float p3 = bperm(addr, ov[2 * ks + 1][r1]);                    \
                float v1 = (lane & 32) ? p3 : p2;                              \
                dw[jp] = packbf(v0, v1);                                       \
            }                                                                  \
            if (ks == 0) B0.i = (int4v){dw[0], dw[1], dw[2], dw[3]};           \
            else         B1.i = (int4v){dw[0], dw[1], dw[2], dw[3]};           \
        }                                                                      \
    }

    #define HLAYER(mb, bb)                                                     \
    BBUILD();                                                                  \
    _Pragma("unroll")                                                          \
    for (int t = 0; t < 4; ++t) {                                              \
        short8v a0 = *(short8v*)&WH[(((mb) * 8 + t * 2 + 0) * 64 + lane) * 8]; \
        short8v a1 = *(short8v*)&WH[(((mb) * 8 + t * 2 + 1) * 64 + lane) * 8]; \
        short8v c0 = *(short8v*)&WH[(((mb + 1) * 8 + t * 2 + 0) * 64 + lane) * 8]; \
        short8v c1 = *(short8v*)&WH[(((mb + 1) * 8 + t * 2 + 1) * 64 + lane) * 8]; \
        f32x4 aa = __builtin_amdgcn_mfma_f32_16x16x32_bf16(a0, B0.s, zf, 0, 0, 0); \
        aa = __builtin_amdgcn_mfma_f32_16x16x32_bf16(a1, B1.s, aa, 0, 0, 0);   \
        f32x4 cc = __builtin_amdgcn_mfma_f32_16x16x32_bf16(c0, B0.s, zf, 0, 0, 0); \
        cc = __builtin_amdgcn_mfma_f32_16x16x32_bf16(c1, B1.s, cc, 0, 0, 0);   \
        accA[t] = aa; accC[t] = cc;                                            \
    }                                                                          \
    _Pragma("unroll")                                                          \
    for (int t = 0; t < 4; ++t) {                                              \
        f32x4 ba = *(f32x4*)&BIAS[(bb) * 64 + 16 * t + 4 * q];                 \
        f32x4 bc = *(f32x4*)&BIAS[(bb + 1) * 64 + 16 * t + 4 * q];             \
        _Pragma("unroll")                                                      \
        for (int r = 0; r < 4; ++r)                                            \
            ov[t][r] = act(fmaf(sv, accA[t][r], ba[r]),                        \
                           fmaf(sv, accC[t][r], bc[r]));                       \
    }

    HLAYER(0, 2)   // W2/W22 + b2/b22
    HLAYER(2, 4)   // W3/W33 + b3/b33
    #undef HLAYER
    #undef BBUILD

    // ---- store: ov[t][r] -> out[node][16t+4q+r], float4 per t (full lines) ----
    float* op = out + (size_t)node * HH + 4 * q;
    #pragma unroll
    for (int t = 0; t < 4; ++t)
        *(f32x4*)(op + 16 * t) = (f32x4){ov[t][0], ov[t][1], ov[t][2], ov[t][3]};
}

extern "C" void kernel_launch(void* const* d_in, const int* in_sizes, int n_in,
                              void* d_out, int out_size, void* d_ws, size_t ws_size,
                              hipStream_t stream) {
    const float* x     = (const float*)d_in[0];
    const float* adj   = (const float*)d_in[1];
    const float* adjk1 = (const float*)d_in[2];
    const float* W1  = (const float*)d_in[3];  const float* b1  = (const float*)d_in[4];
    const float* W11 = (const float*)d_in[5];  const float* b11 = (const float*)d_in[6];
    const float* W2  = (const float*)d_in[7];  const float* b2  = (const float*)d_in[8];
    const float* W22 = (const float*)d_in[9];  const float* b22 = (const float*)d_in[10];
    const float* W3  = (const float*)d_in[11]; const float* b3  = (const float*)d_in[12];
    const float* W33 = (const float*)d_in[13]; const float* b33 = (const float*)d_in[14];
    float* out = (float*)d_out;
    float* s = (float*)d_ws;  // 5000 floats scratch

    s_kernel<<<NV, 256, 0, stream>>>(adj, adjk1, s);
    gcn_kernel<<<BLOCKS, 512, 0, stream>>>(x, s, W1, b1, W11, b11,
                                           W2, b2, W22, b22, W3, b3, W33, b33, out);
}

// Round 10
// 45.642 us; speedup vs baseline: 5.4930x; 1.0029x over previous
//
#include <hip/hip_runtime.h>
#include <math.h>

#define NV 5000   // nodes
#define BATCH 16
#define DD 12     // input feature dim
#define HH 64     // hidden dim
#define KK 30     // virtual nodes
#define NODES (BATCH * NV)   // 80000
#define NGRP (NODES / 32)    // 2500 wave-groups (32 nodes each)
#define BLOCKS (NGRP / 4)    // 625 blocks x 4 waves (exact)

typedef __attribute__((ext_vector_type(8))) short short8v;  // 8 bf16 (4 VGPR)
typedef __attribute__((ext_vector_type(4))) float f32x4;
typedef __attribute__((ext_vector_type(4))) int int4v;
union I4S8 { int4v i; short8v s; };

// ---------------- Kernel A: s[m] = adj[m,m] / deg[m] ----------------
__global__ __launch_bounds__(256) void s_kernel(const float* __restrict__ adj,
                                                const float* __restrict__ adjk1,
                                                float* __restrict__ s) {
    const int m = blockIdx.x;
    const float4* row = reinterpret_cast<const float4*>(adj + (size_t)m * NV);
    float acc = 0.f;
    for (int i = threadIdx.x; i < NV / 4; i += 256) {
        float4 v = row[i];
        acc += (v.x + v.y) + (v.z + v.w);
    }
    for (int off = 32; off > 0; off >>= 1) acc += __shfl_down(acc, off, 64);
    __shared__ float part[4];
    if ((threadIdx.x & 63) == 0) part[threadIdx.x >> 6] = acc;
    __syncthreads();
    if (threadIdx.x == 0) {
        float deg = (part[0] + part[1]) + (part[2] + part[3]);
        float cs = 0.f;
        #pragma unroll
        for (int k = 0; k < KK; ++k) cs += adjk1[(size_t)k * NV + m];
        deg += cs;
        s[m] = adj[(size_t)m * NV + m] / deg;
    }
}

// ---------------- helpers ----------------
__device__ __forceinline__ unsigned short bf16rne(float f) {
    unsigned u = __float_as_uint(f);
    u += 0x7FFFu + ((u >> 16) & 1u);          // round-to-nearest-even
    return (unsigned short)(u >> 16);
}
__device__ __forceinline__ int packbf(float lo, float hi) {
    return (int)((unsigned)bf16rne(lo) | ((unsigned)bf16rne(hi) << 16));
}
__device__ __forceinline__ float bperm(int addr, float v) {
    return __int_as_float(__builtin_amdgcn_ds_bpermute(addr, __float_as_int(v)));
}
// tanh(A)*sigmoid(C); args ~1e-3. Taylor exact to fp32 rounding for |x|<=0.04;
// cold fallback uses libm tanhf (expf-tanh flushes tiny args -> round-0 bug).
__device__ __forceinline__ float act(float A, float C) {
    float a2 = A * A;
    float th = A * fmaf(a2, fmaf(a2, 0.13333334f, -0.33333334f), 1.0f);
    float c2 = C * C;
    float sg = fmaf(C, fmaf(c2, -0.020833334f, 0.25f), 0.5f);
    if (__builtin_expect(fabsf(A) > 0.04f, 0)) th = tanhf(A);
    if (__builtin_expect(fabsf(C) > 0.04f, 0)) sg = 1.0f / (1.0f + __expf(-C));
    return th * sg;
}

// ---------------- Kernel B: MFMA, swapped orientation, 32 nodes/wave -------
// Two 16-node sub-groups per wave SHARE all A-frag (weight) reads -> frag-DS
// per node halved vs round 9, and every MFMA chain has an independent twin
// (ILP covers the 2.4-waves/SIMD TLP). Accumulators live only inside one
// t-iteration (fused epilogue) -> ~110 live VGPRs; sched_barrier(0) per t
// stops frag-read hoisting. Numerics identical to round 9 (same chains).
//  A-frag(mat,t,ks): lane supplies W[k][16t+(lane&15)], k=32ks+(lane>>4)*8+j
//  B-frag(ks):       lane supplies o[k][node], node=lane&15
//  D: ch = 16t+4q+r (q=lane>>4), node = lane&15   [m89-verified]
__global__ __launch_bounds__(256, 3) void gcn_kernel(
    const float* __restrict__ x, const float* __restrict__ s,
    const float* __restrict__ W1, const float* __restrict__ b1,
    const float* __restrict__ W11, const float* __restrict__ b11,
    const float* __restrict__ W2, const float* __restrict__ b2,
    const float* __restrict__ W22, const float* __restrict__ b22,
    const float* __restrict__ W3, const float* __restrict__ b3,
    const float* __restrict__ W33, const float* __restrict__ b33,
    float* __restrict__ out) {
    __shared__ unsigned short WH[4 * 8 * 64 * 8];   // W2,W22,W3,W33 frags: 32 KiB
    __shared__ unsigned short WL[2 * 4 * 64 * 8];   // W1,W11 frags (K-padded): 8 KiB
    __shared__ float BIAS[6 * 64];                  // 1.5 KiB

    const int tid = threadIdx.x;

    // ---- stage H-layer weights into frag order (coalesced reads) ----
    {
        const float* HM[4] = {W2, W22, W3, W33};
        #pragma unroll
        for (int m = 0; m < 4; ++m) {
            const float* Wp = HM[m];
            for (int e = tid; e < 4096; e += 256) {
                const int k = e >> 6, c = e & 63;
                const int dst = ((m * 8 + (c >> 4) * 2 + (k >> 5)) * 64 +
                                 ((k >> 3) & 3) * 16 + (c & 15)) * 8 + (k & 7);
                WH[dst] = bf16rne(Wp[e]);
            }
        }
    }
    for (int e = tid; e < 2048; e += 256) *(unsigned*)&WL[e * 2] = 0u;  // zero-pad K
    for (int e = tid; e < 384; e += 256) {
        const float* bp = (e < 64) ? b1 : (e < 128) ? b11 : (e < 192) ? b2
                        : (e < 256) ? b22 : (e < 320) ? b3 : b33;
        BIAS[e] = bp[e & 63];
    }
    __syncthreads();
    #pragma unroll
    for (int m = 0; m < 2; ++m) {
        const float* Wp = (m == 0) ? W1 : W11;
        for (int e = tid; e < 768; e += 256) {
            const int k = e >> 6, c = e & 63;
            const int dst = ((m * 4 + (c >> 4)) * 64 +
                             ((k >> 3) & 3) * 16 + (c & 15)) * 8 + (k & 7);
            WL[dst] = bf16rne(Wp[e]);
        }
    }
    __syncthreads();

    const int lane = tid & 63, wid = tid >> 6;
    const int q = lane >> 4, col = lane & 15;
    const int G = blockIdx.x * 4 + wid;        // group id [0,2500)
    const int node0 = G * 32 + col;            // sub-group 0 node (b*NV+m)
    const int node1 = node0 + 16;              // sub-group 1 node
    const float sv0 = s[node0 % NV];
    const float sv1 = s[node1 % NV];
    const int A0 = (32 * (q & 1) + col) * 4;   // bperm addr, j<4
    const int A1 = A0 + 64;                    //              j>=4
    const f32x4 zf = {0.f, 0.f, 0.f, 0.f};

    // ---- Layer 1 B-frags: x (fp32 -> bf16), K padded 12->32 ----
    I4S8 bx0, bx1;
    {
        f32x4 xa = zf, xb = zf;
        const float* xp = x + (size_t)node0 * DD;
        if (q == 0) { xa = *(const f32x4*)(xp); xb = *(const f32x4*)(xp + 4); }
        else if (q == 1) { xa = *(const f32x4*)(xp + 8); }
        bx0.i = (int4v){packbf(xa[0], xa[1]), packbf(xa[2], xa[3]),
                        packbf(xb[0], xb[1]), packbf(xb[2], xb[3])};
        xa = zf; xb = zf;
        const float* xq = x + (size_t)node1 * DD;
        if (q == 0) { xa = *(const f32x4*)(xq); xb = *(const f32x4*)(xq + 4); }
        else if (q == 1) { xa = *(const f32x4*)(xq + 8); }
        bx1.i = (int4v){packbf(xa[0], xa[1]), packbf(xa[2], xa[3]),
                        packbf(xb[0], xb[1]), packbf(xb[2], xb[3])};
    }

    float ov0[4][4], ov1[4][4];

    // ---- Layer 1 ----
    #pragma unroll
    for (int t = 0; t < 4; ++t) {
        short8v a0 = *(short8v*)&WL[((0 * 4 + t) * 64 + lane) * 8];
        short8v a1 = *(short8v*)&WL[((1 * 4 + t) * 64 + lane) * 8];
        f32x4 aa0 = __builtin_amdgcn_mfma_f32_16x16x32_bf16(a0, bx0.s, zf, 0, 0, 0);
        f32x4 cc0 = __builtin_amdgcn_mfma_f32_16x16x32_bf16(a1, bx0.s, zf, 0, 0, 0);
        f32x4 aa1 = __builtin_amdgcn_mfma_f32_16x16x32_bf16(a0, bx1.s, zf, 0, 0, 0);
        f32x4 cc1 = __builtin_amdgcn_mfma_f32_16x16x32_bf16(a1, bx1.s, zf, 0, 0, 0);
        f32x4 ba = *(f32x4*)&BIAS[0 * 64 + 16 * t + 4 * q];
        f32x4 bc = *(f32x4*)&BIAS[1 * 64 + 16 * t + 4 * q];
        #pragma unroll
        for (int r = 0; r < 4; ++r) {
            ov0[t][r] = act(fmaf(sv0, aa0[r], ba[r]), fmaf(sv0, cc0[r], bc[r]));
            ov1[t][r] = act(fmaf(sv1, aa1[r], ba[r]), fmaf(sv1, cc1[r], bc[r]));
        }
        __builtin_amdgcn_sched_barrier(0);
    }

    I4S8 B00, B10, B01, B11v;
    #define BBUILD(OV, B0v, B1v)                                               \
    {                                                                          \
        _Pragma("unroll")                                                      \
        for (int ks = 0; ks < 2; ++ks) {                                       \
            int dw[4];                                                         \
            _Pragma("unroll")                                                  \
            for (int jp = 0; jp < 4; ++jp) {                                   \
                const int addr = (jp < 2) ? A0 : A1;                           \
                const int r0 = (2 * jp) & 3, r1 = (2 * jp + 1) & 3;            \
                float p0 = bperm(addr, OV[2 * ks][r0]);                        \
                float p1 = bperm(addr, OV[2 * ks + 1][r0]);                    \
                float v0 = (lane & 32) ? p1 : p0;                              \
                float p2 = bperm(addr, OV[2 * ks][r1]);                        \
                float p3 = bperm(addr, OV[2 * ks + 1][r1]);                    \
                float v1 = (lane & 32) ? p3 : p2;                              \
                dw[jp] = packbf(v0, v1);                                       \
            }                                                                  \
            if (ks == 0) B0v.i = (int4v){dw[0], dw[1], dw[2], dw[3]};          \
            else         B1v.i = (int4v){dw[0], dw[1], dw[2], dw[3]};          \
        }                                                                      \
    }

    #define HLAYER(mb, bb)                                                     \
    BBUILD(ov0, B00, B10);                                                     \
    BBUILD(ov1, B01, B11v);                                                    \
    _Pragma("unroll")                                                          \
    for (int t = 0; t < 4; ++t) {                                              \
        short8v a0 = *(short8v*)&WH[(((mb) * 8 + t * 2 + 0) * 64 + lane) * 8]; \
        short8v a1 = *(short8v*)&WH[(((mb) * 8 + t * 2 + 1) * 64 + lane) * 8]; \
        f32x4 aa0 = __builtin_amdgcn_mfma_f32_16x16x32_bf16(a0, B00.s, zf, 0, 0, 0); \
        aa0 = __builtin_amdgcn_mfma_f32_16x16x32_bf16(a1, B10.s, aa0, 0, 0, 0);\
        f32x4 aa1 = __builtin_amdgcn_mfma_f32_16x16x32_bf16(a0, B01.s, zf, 0, 0, 0); \
        aa1 = __builtin_amdgcn_mfma_f32_16x16x32_bf16(a1, B11v.s, aa1, 0, 0, 0);\
        short8v c0 = *(short8v*)&WH[(((mb + 1) * 8 + t * 2 + 0) * 64 + lane) * 8]; \
        short8v c1 = *(short8v*)&WH[(((mb + 1) * 8 + t * 2 + 1) * 64 + lane) * 8]; \
        f32x4 cc0 = __builtin_amdgcn_mfma_f32_16x16x32_bf16(c0, B00.s, zf, 0, 0, 0); \
        cc0 = __builtin_amdgcn_mfma_f32_16x16x32_bf16(c1, B10.s, cc0, 0, 0, 0);\
        f32x4 cc1 = __builtin_amdgcn_mfma_f32_16x16x32_bf16(c0, B01.s, zf, 0, 0, 0); \
        cc1 = __builtin_amdgcn_mfma_f32_16x16x32_bf16(c1, B11v.s, cc1, 0, 0, 0);\
        f32x4 ba = *(f32x4*)&BIAS[(bb) * 64 + 16 * t + 4 * q];                 \
        f32x4 bc = *(f32x4*)&BIAS[(bb + 1) * 64 + 16 * t + 4 * q];             \
        _Pragma("unroll")                                                      \
        for (int r = 0; r < 4; ++r) {                                          \
            ov0[t][r] = act(fmaf(sv0, aa0[r], ba[r]), fmaf(sv0, cc0[r], bc[r]));\
            ov1[t][r] = act(fmaf(sv1, aa1[r], ba[r]), fmaf(sv1, cc1[r], bc[r]));\
        }                                                                      \
        __builtin_amdgcn_sched_barrier(0);                                     \
    }

    HLAYER(0, 2)   // W2/W22 + b2/b22
    HLAYER(2, 4)   // W3/W33 + b3/b33
    #undef HLAYER
    #undef BBUILD

    // ---- store: ov_h[t][r] -> out[node_h][16t+4q+r] ----
    float* op0 = out + (size_t)node0 * HH + 4 * q;
    float* op1 = out + (size_t)node1 * HH + 4 * q;
    #pragma unroll
    for (int t = 0; t < 4; ++t) {
        *(f32x4*)(op0 + 16 * t) = (f32x4){ov0[t][0], ov0[t][1], ov0[t][2], ov0[t][3]};
        *(f32x4*)(op1 + 16 * t) = (f32x4){ov1[t][0], ov1[t][1], ov1[t][2], ov1[t][3]};
    }
}

extern "C" void kernel_launch(void* const* d_in, const int* in_sizes, int n_in,
                              void* d_out, int out_size, void* d_ws, size_t ws_size,
                              hipStream_t stream) {
    const float* x     = (const float*)d_in[0];
    const float* adj   = (const float*)d_in[1];
    const float* adjk1 = (const float*)d_in[2];
    const float* W1  = (const float*)d_in[3];  const float* b1  = (const float*)d_in[4];
    const float* W11 = (const float*)d_in[5];  const float* b11 = (const float*)d_in[6];
    const float* W2  = (const float*)d_in[7];  const float* b2  = (const float*)d_in[8];
    const float* W22 = (const float*)d_in[9];  const float* b22 = (const float*)d_in[10];
    const float* W3  = (const float*)d_in[11]; const float* b3  = (const float*)d_in[12];
    const float* W33 = (const float*)d_in[13]; const float* b33 = (const float*)d_in[14];
    float* out = (float*)d_out;
    float* s = (float*)d_ws;  // 5000 floats scratch

    s_kernel<<<NV, 256, 0, stream>>>(adj, adjk1, s);
    gcn_kernel<<<BLOCKS, 256, 0, stream>>>(x, s, W1, b1, W11, b11,
                                           W2, b2, W22, b22, W3, b3, W33, b33, out);
}